// Round 18
// baseline (155.779 us; speedup 1.0000x reference)
//
#include <hip/hip_runtime.h>
#include <hip/hip_bf16.h>
#include <math.h>

#define N 8192
#define D 256
#define MARGIN 1.0f

#define BM 128
#define BN 128
#define NCH 4            // K-chunks of 64 fp16 elems (128B per row)
#define NB (N / BM)      // 64
#define NTRI (NB * (NB + 1) / 2)   // 2080
#define NCONV (N * D / 4 / 256)    // 2048 conversion blocks
#define DPB 512          // d_pos blocks (one per class)
#define CCAP 64          // class member capacity (mean 16)
#define RPITCH 257       // padded row pitch (floats) -> conflict-free LDS

typedef __attribute__((ext_vector_type(8))) _Float16 half8;
typedef __attribute__((ext_vector_type(4))) _Float16 half4;
typedef __attribute__((ext_vector_type(4))) float f32x4;
typedef unsigned int uint32;
typedef unsigned long long u64;

// ---------------------------------------------------------------------------
// k_conv: f32 -> fp16 plane; block 0 zeroes the coordination cells.
// ---------------------------------------------------------------------------
__global__ __launch_bounds__(256) void k_conv(const float* __restrict__ x,
                                              _Float16* __restrict__ hp,
                                              u64* __restrict__ acc_pack,
                                              unsigned* __restrict__ counter,
                                              unsigned* __restrict__ done1,
                                              unsigned* __restrict__ done2) {
    int i = blockIdx.x * 256 + threadIdx.x;
    float4 v = reinterpret_cast<const float4*>(x)[i];
    half4 h;
    h[0] = (_Float16)v.x; h[1] = (_Float16)v.y;
    h[2] = (_Float16)v.z; h[3] = (_Float16)v.w;
    reinterpret_cast<half4*>(hp)[i] = h;
    if (blockIdx.x == 0 && threadIdx.x == 0) {
        *acc_pack = 0ull;
        *counter = 0u;
        *done1 = 0u;
        *done2 = 0u;
    }
}

// ---------------------------------------------------------------------------
// k_fused: blocks [0,DPB) = per-class exact-f32 d_pos (LDS-resident),
// agent-relaxed dpos publish, done1++. Blocks [DPB,DPB+NTRI) = r15-proven
// tile GEMM; polls done1 AFTER the K-loop; agent-relaxed partial publish
// (no threadfence); done2++. Blocks [DPB+NTRI,+NB) = finish: spin on done2,
// fold partials, packed-integer atomicAdd, last block writes out.
// One overlaid 71680 B LDS arena; LDS pointers via offset macros (pointer
// ARRAYS of LDS casts don't compile on hipcc).
// ---------------------------------------------------------------------------
__global__ __launch_bounds__(512) void k_fused(const float* __restrict__ x,
                                               const _Float16* __restrict__ hp,
                                               const int* __restrict__ labels,
                                               float* __restrict__ dpos,
                                               float* __restrict__ pr_n,
                                               float* __restrict__ pr_s,
                                               float* __restrict__ pc_n,
                                               float* __restrict__ pc_s,
                                               u64* __restrict__ acc_pack,
                                               unsigned* __restrict__ counter,
                                               unsigned* __restrict__ done1,
                                               unsigned* __restrict__ done2,
                                               float* __restrict__ out) {
    __shared__ __align__(16) char SMEM[71680];
    const int t = threadIdx.x;
    const float NINF = -__builtin_inff();

    if (blockIdx.x < DPB) {
        // ================= d_pos class block =================
        float* rows = (float*)SMEM;                    // 64*257*4 = 65792 B
        float* sqv  = (float*)(SMEM + 65792);
        int*   dpv  = (int*)(SMEM + 66048);
        int*   mem  = (int*)(SMEM + 66304);
        int*   nmem = (int*)(SMEM + 66560);

        const int c = blockIdx.x;
        if (t == 0) *nmem = 0;
        if (t < CCAP) dpv[t] = 0;
        __syncthreads();
        for (int base = 0; base < N; base += 512) {
            int j = base + t;
            if (labels[j] == c) {
                int p = atomicAdd(nmem, 1);
                if (p < CCAP) mem[p] = j;
            }
        }
        __syncthreads();
        const int M = *nmem < CCAP ? *nmem : CCAP;

        if (t < 256)
            for (int r = 0; r < M; ++r)
                rows[r * RPITCH + t] = x[(size_t)mem[r] * D + t];
        __syncthreads();

        if (t < M) {
            const float* rp = &rows[t * RPITCH];
            float s = 0.0f;
            for (int d = 0; d < D; ++d) s += rp[d] * rp[d];
            sqv[t] = s;
        }
        __syncthreads();

        for (int p = t; p < M * M; p += 512) {
            int i = p / M, j = p - i * M;
            const float* ri = &rows[i * RPITCH];
            const float* rj = &rows[j * RPITCH];
            float dot = 0.0f;
            for (int d = 0; d < D; ++d) dot = fmaf(ri[d], rj[d], dot);
            float sqd = fmaxf(sqv[i] + sqv[j] - 2.0f * dot, 0.0f);
            if (j != i) atomicMax(&dpv[i], __float_as_int(sqd));
        }
        __syncthreads();
        if (t < M) {
            float v = (M > 1) ? sqrtf(__int_as_float(dpv[t])) : -1.0f;
            __hip_atomic_store(&dpos[mem[t]], v, __ATOMIC_RELAXED,
                               __HIP_MEMORY_SCOPE_AGENT);
        }
        __syncthreads();
        if (t == 0) atomicAdd(done1, 1u);
        return;
    }

    if (blockIdx.x >= DPB + NTRI) {
        // ================= finish tail block =================
        float* shn = (float*)SMEM;                 // [4][128]
        float* shs = (float*)(SMEM + 2048);        // [4][128]
        u64*   wpart = (u64*)(SMEM + 4096);
        const int q = blockIdx.x - DPB - NTRI;
        const int part = t >> 7, a = t & 127;
        const int Lr = NB - q;
        const int base = q * NB - q * (q - 1) / 2;
        const int ntiles = Lr + q + 1;

        if (t == 0) {
            while (__hip_atomic_load(done2, __ATOMIC_RELAXED,
                                     __HIP_MEMORY_SCOPE_AGENT) < NTRI)
                __builtin_amdgcn_s_sleep(8);
        }
        __syncthreads();

        float an = NINF, ag = NINF;
        for (int u = part; u < ntiles; u += 4) {
            size_t off;
            const float *Pn, *Ps;
            if (u < Lr) {
                off = (size_t)(base + u) * BM + a;
                Pn = pr_n; Ps = pr_s;
            } else {
                int byy = u - Lr;
                int tb2 = byy * NB - byy * (byy - 1) / 2 + (q - byy);
                off = (size_t)tb2 * BN + a;
                Pn = pc_n; Ps = pc_s;
            }
            an = fmaxf(an, __hip_atomic_load(&Pn[off], __ATOMIC_RELAXED,
                                             __HIP_MEMORY_SCOPE_AGENT));
            ag = fmaxf(ag, __hip_atomic_load(&Ps[off], __ATOMIC_RELAXED,
                                             __HIP_MEMORY_SCOPE_AGENT));
        }
        shn[part * 128 + a] = an;
        shs[part * 128 + a] = ag;
        __syncthreads();

        u64 pack = 0;
        if (t < 128) {
            an = fmaxf(fmaxf(shn[t], shn[128 + t]),
                       fmaxf(shn[256 + t], shn[384 + t]));
            ag = fmaxf(fmaxf(shs[t], shs[128 + t]),
                       fmaxf(shs[256 + t], shs[384 + t]));
            float dp = __hip_atomic_load(&dpos[q * 128 + t], __ATOMIC_RELAXED,
                                         __HIP_MEMORY_SCOPE_AGENT);
            if (dp >= 0.0f && an > -1e37f) {
                float dphi = dp + MARGIN;
                float aLo = (2.0f - dphi * dphi) * 0.5f;
                float asel = (ag > aLo) ? ag : an;
                float fsq = fmaxf(fmaf(-2.0f, asel, 2.0f), 0.0f);
                float dn = sqrtf(fsq);
                float l = fmaxf(dp - dn + MARGIN, 0.0f);
                u64 lq = (u64)(l * 1073741824.0f + 0.5f);
                pack = (lq << 16) | 1ull;
            }
        }
        for (int m = 1; m <= 32; m <<= 1) pack += __shfl_xor(pack, m, 64);
        if (t < 128 && (t & 63) == 0) wpart[t >> 6] = pack;
        __syncthreads();
        if (t == 0) {
            atomicAdd(acc_pack, wpart[0] + wpart[1]);
            __threadfence();
            unsigned old = atomicAdd(counter, 1u);
            if (old == NB - 1) {
                u64 val = atomicAdd(acc_pack, (u64)0);
                double s = (double)(val >> 16) * (1.0 / 1073741824.0);
                double c = (double)(val & 0xFFFFull);
                out[0] = (float)(s / c);
            }
        }
        return;
    }

    // ================= tile block (r15 core) =================
#define ABUF(i) (SMEM + (i) * 16384)
#define BBUF(i) (SMEM + 32768 + (i) * 16384)
    float* rHi = (float*)(SMEM + 65536);
    float* cHi = (float*)(SMEM + 66048);
    int* rlab = (int*)(SMEM + 66560);
    int* clab = (int*)(SMEM + 67072);
    float* tmpn = (float*)(SMEM + 67584);   // [4][128]
    float* tmps = (float*)(SMEM + 69632);   // [4][128]

    int tb = blockIdx.x - DPB;
    int by = (int)((2 * NB + 1 - sqrtf((float)((2 * NB + 1) * (2 * NB + 1)) -
                                       8.0f * (float)tb)) * 0.5f);
    if (by < 0) by = 0;
    if (by > NB - 1) by = NB - 1;
    while (by > 0 && (by * NB - by * (by - 1) / 2) > tb) --by;
    while (((by + 1) * NB - (by + 1) * by / 2) <= tb) ++by;
    const int bx = by + (tb - (by * NB - by * (by - 1) / 2));
    const int r0 = by * BM, c0 = bx * BN;

    const int w = t >> 6, lane = t & 63;
    const int wr = w >> 2, wc = w & 3;   // 2x4 wave grid; 64x32 per wave

    if (t < BM) rlab[t] = labels[r0 + t];
    else if (t < 256) clab[t - BM] = labels[c0 + t - BM];

    f32x4 acc[4][2] = {};    // [m][n]
    f32x4 accT[2][4] = {};   // [n][m]

    const int srow = lane >> 3;
    const int scol = ((lane & 7) ^ srow) << 3;   // fp16-elem offset
    const _Float16* gA0 = hp + (size_t)(r0 + srow) * D + scol + (size_t)w * 8 * D;
    const _Float16* gB0 = hp + (size_t)(c0 + srow) * D + scol + (size_t)w * 8 * D;
    const int ldso = w * 1024 + lane * 16;

#define STAGE(cu, k0e)                                                          \
    {                                                                           \
        _Pragma("unroll")                                                       \
        for (int q2 = 0; q2 < 2; ++q2) {                                        \
            const _Float16* gpa = gA0 + q2 * (8 * 8 * D) + (k0e);               \
            const _Float16* gpb = gB0 + q2 * (8 * 8 * D) + (k0e);               \
            char* lpa = ABUF(cu) + q2 * 8192 + ldso;                            \
            char* lpb = BBUF(cu) + q2 * 8192 + ldso;                            \
            __builtin_amdgcn_global_load_lds(                                   \
                (__attribute__((address_space(1))) void*)(void*)gpa,            \
                (__attribute__((address_space(3))) void*)lpa, 16, 0, 0);        \
            __builtin_amdgcn_global_load_lds(                                   \
                (__attribute__((address_space(1))) void*)(void*)gpb,            \
                (__attribute__((address_space(3))) void*)lpb, 16, 0, 0);        \
        }                                                                       \
    }

    STAGE(0, 0);
    asm volatile("s_waitcnt vmcnt(0)" ::: "memory");
    __syncthreads();

    const int g2 = lane >> 4;
    const int lr = lane & 15;
    const int rsw = lr & 7;

#pragma unroll 1
    for (int s = 0; s < NCH; ++s) {
        const int cur = s & 1;
        if (s < NCH - 1) STAGE(cur ^ 1, (s + 1) * 64);

#pragma unroll
        for (int kk = 0; kk < 2; ++kk) {
            const int cb = kk * 64 + (g2 << 4);
            half8 aF[4], bF[2];
#pragma unroll
            for (int m = 0; m < 4; ++m) {
                int ra = wr * 64 + m * 16 + lr;
                aF[m] = *reinterpret_cast<const half8*>(
                    ABUF(cur) + ra * 128 + (cb ^ (rsw << 4)));
            }
#pragma unroll
            for (int n = 0; n < 2; ++n) {
                int rb = wc * 32 + n * 16 + lr;
                bF[n] = *reinterpret_cast<const half8*>(
                    BBUF(cur) + rb * 128 + (cb ^ (rsw << 4)));
            }
#pragma unroll
            for (int m = 0; m < 4; ++m)
#pragma unroll
                for (int n = 0; n < 2; ++n)
                    acc[m][n] = __builtin_amdgcn_mfma_f32_16x16x32_f16(
                        aF[m], bF[n], acc[m][n], 0, 0, 0);
#pragma unroll
            for (int n = 0; n < 2; ++n)
#pragma unroll
                for (int m = 0; m < 4; ++m)
                    accT[n][m] = __builtin_amdgcn_mfma_f32_16x16x32_f16(
                        bF[n], aF[m], accT[n][m], 0, 0, 0);
        }
        __syncthreads();
    }
#undef STAGE
#undef ABUF
#undef BBUF

    // ---- wait for dpos (dpos blocks finished during K-loop), thresholds ----
    if (t == 0) {
        while (__hip_atomic_load(done1, __ATOMIC_RELAXED,
                                 __HIP_MEMORY_SCOPE_AGENT) < DPB)
            __builtin_amdgcn_s_sleep(2);
    }
    __syncthreads();
    if (t < BM) {
        float dp = __hip_atomic_load(&dpos[r0 + t], __ATOMIC_RELAXED,
                                     __HIP_MEMORY_SCOPE_AGENT);
        rHi[t] = (2.0f - dp * dp) * 0.5f;   // a < aHi <=> dist > dp
    } else if (t < 256) {
        int u = t - BM;
        float dp = __hip_atomic_load(&dpos[c0 + u], __ATOMIC_RELAXED,
                                     __HIP_MEMORY_SCOPE_AGENT);
        cHi[u] = (2.0f - dp * dp) * 0.5f;
    }
    __syncthreads();

    // ---- epilogue: key-free float maxima (r15-proven) ----
    int rowm[4]; int rlm[4]; float rHim[4];
#pragma unroll
    for (int m = 0; m < 4; ++m) {
        rowm[m] = wr * 64 + m * 16 + lr;
        rlm[m] = rlab[rowm[m]];
        rHim[m] = rHi[rowm[m]];
    }
    int4 clA = *reinterpret_cast<const int4*>(&clab[wc * 32 + g2 * 4]);
    int4 clB = *reinterpret_cast<const int4*>(&clab[wc * 32 + 16 + g2 * 4]);
    const int clv[8] = {clA.x, clA.y, clA.z, clA.w, clB.x, clB.y, clB.z, clB.w};
    int coln[2]; int cln[2]; float cHin[2];
#pragma unroll
    for (int n = 0; n < 2; ++n) {
        coln[n] = wc * 32 + n * 16 + lr;
        cln[n] = clab[coln[n]];
        cHin[n] = cHi[coln[n]];
    }
    int rlq[16];
#pragma unroll
    for (int m = 0; m < 4; ++m) {
        int4 rv = *reinterpret_cast<const int4*>(&rlab[wr * 64 + m * 16 + g2 * 4]);
        rlq[m * 4 + 0] = rv.x; rlq[m * 4 + 1] = rv.y;
        rlq[m * 4 + 2] = rv.z; rlq[m * 4 + 3] = rv.w;
    }

    // row pass via accT
#pragma unroll
    for (int m = 0; m < 4; ++m) {
        const int rl = rlm[m];
        const float aHi = rHim[m];
        float an = NINF, ag = NINF;
#pragma unroll
        for (int n = 0; n < 2; ++n)
#pragma unroll
            for (int reg = 0; reg < 4; ++reg) {
                float a = accT[n][m][reg];
                bool neq = (rl != clv[n * 4 + reg]);
                an = fmaxf(an, neq ? a : NINF);
                ag = fmaxf(ag, (neq && a < aHi) ? a : NINF);
            }
        an = fmaxf(an, __shfl_xor(an, 16, 64));
        an = fmaxf(an, __shfl_xor(an, 32, 64));
        ag = fmaxf(ag, __shfl_xor(ag, 16, 64));
        ag = fmaxf(ag, __shfl_xor(ag, 32, 64));
        if (g2 == 0) {
            tmpn[wc * 128 + rowm[m]] = an;
            tmps[wc * 128 + rowm[m]] = ag;
        }
    }
    __syncthreads();
    if (t < BM) {
        float a0 = fmaxf(tmpn[t], tmpn[128 + t]);
        float a1 = fmaxf(tmpn[256 + t], tmpn[384 + t]);
        __hip_atomic_store(&pr_n[(size_t)tb * BM + t], fmaxf(a0, a1),
                           __ATOMIC_RELAXED, __HIP_MEMORY_SCOPE_AGENT);
        float b0 = fmaxf(tmps[t], tmps[128 + t]);
        float b1 = fmaxf(tmps[256 + t], tmps[384 + t]);
        __hip_atomic_store(&pr_s[(size_t)tb * BM + t], fmaxf(b0, b1),
                           __ATOMIC_RELAXED, __HIP_MEMORY_SCOPE_AGENT);
    }
    __syncthreads();

    // col pass via acc
#pragma unroll
    for (int n = 0; n < 2; ++n) {
        const int cl = cln[n];
        const float aHi = cHin[n];
        float an = NINF, ag = NINF;
#pragma unroll
        for (int m = 0; m < 4; ++m)
#pragma unroll
            for (int reg = 0; reg < 4; ++reg) {
                float a = acc[m][n][reg];
                bool neq = (cl != rlq[m * 4 + reg]);
                an = fmaxf(an, neq ? a : NINF);
                ag = fmaxf(ag, (neq && a < aHi) ? a : NINF);
            }
        an = fmaxf(an, __shfl_xor(an, 16, 64));
        an = fmaxf(an, __shfl_xor(an, 32, 64));
        ag = fmaxf(ag, __shfl_xor(ag, 16, 64));
        ag = fmaxf(ag, __shfl_xor(ag, 32, 64));
        if (lane < 16) {
            tmpn[wr * 128 + coln[n]] = an;
            tmps[wr * 128 + coln[n]] = ag;
        }
    }
    __syncthreads();
    if (t < BN) {
        __hip_atomic_store(&pc_n[(size_t)tb * BN + t],
                           fmaxf(tmpn[t], tmpn[128 + t]),
                           __ATOMIC_RELAXED, __HIP_MEMORY_SCOPE_AGENT);
        __hip_atomic_store(&pc_s[(size_t)tb * BN + t],
                           fmaxf(tmps[t], tmps[128 + t]),
                           __ATOMIC_RELAXED, __HIP_MEMORY_SCOPE_AGENT);
    }
    __syncthreads();                       // drains vmcnt: agent stores done
    if (t == 0) atomicAdd(done2, 1u);      // no threadfence (no wbl2)
}

// ---------------------------------------------------------------------------
extern "C" void kernel_launch(void* const* d_in, const int* in_sizes, int n_in,
                              void* d_out, int out_size, void* d_ws, size_t ws_size,
                              hipStream_t stream) {
    const float* x = (const float*)d_in[0];
    const int* labels = (const int*)d_in[1];
    float* out = (float*)d_out;

    // ws: acc_pack u64 | counter u32 | done1 u32 | done2 u32 | pad | dpos[N]
    // | hp[N*D] fp16 | pr_n | pr_s | pc_n | pc_s (f32, 1.06MB each)
    u64* acc_pack = (u64*)d_ws;
    unsigned* counter = (unsigned*)(acc_pack + 1);
    unsigned* done1 = counter + 1;
    unsigned* done2 = counter + 2;
    float* dpos = (float*)(counter + 4);          // 8B aligned region start
    _Float16* hp = (_Float16*)(dpos + N);
    float* pr_n = (float*)(hp + (size_t)N * D);
    float* pr_s = pr_n + (size_t)NTRI * BM;
    float* pc_n = pr_s + (size_t)NTRI * BM;
    float* pc_s = pc_n + (size_t)NTRI * BM;

    hipLaunchKernelGGL(k_conv, dim3(NCONV), dim3(256), 0, stream,
                       x, hp, acc_pack, counter, done1, done2);
    hipLaunchKernelGGL(k_fused, dim3(DPB + NTRI + NB), dim3(512), 0, stream,
                       x, hp, labels, dpos, pr_n, pr_s, pc_n, pc_s,
                       acc_pack, counter, done1, done2, out);
}

// Round 19
// 96.893 us; speedup vs baseline: 1.6077x; 1.6077x over previous
//
#include <hip/hip_runtime.h>
#include <hip/hip_bf16.h>
#include <math.h>

#define N 8192
#define D 256
#define MARGIN 1.0f

#define BM 128
#define BN 128
#define NCH 4            // K-chunks of 64 fp16 elems (128B per row)
#define NB (N / BM)      // 64
#define NTRI (NB * (NB + 1) / 2)   // 2080
#define NCONV (N * D / 4 / 256)    // 2048 conversion blocks
#define NCLS 512
#define CCAP 64          // class member capacity (mean 16)
#define RPITCH 257       // padded row pitch (floats) -> conflict-free LDS

typedef __attribute__((ext_vector_type(8))) _Float16 half8;
typedef __attribute__((ext_vector_type(4))) _Float16 half4;
typedef __attribute__((ext_vector_type(4))) float f32x4;
typedef unsigned int uint32;
typedef unsigned long long u64;

// ---------------------------------------------------------------------------
// k_prep: blocks [0,NCONV): f32->fp16 conversion (+ block 0 zeroes the
// finish cells). Blocks [NCONV,+NCLS): per-class exact-f32 d_pos,
// LDS-resident (r15-proven).
// ---------------------------------------------------------------------------
__global__ __launch_bounds__(256) void k_prep(const float* __restrict__ x,
                                              const int* __restrict__ labels,
                                              _Float16* __restrict__ hp,
                                              float* __restrict__ dpos,
                                              u64* __restrict__ acc_pack,
                                              unsigned* __restrict__ counter) {
    const int b = blockIdx.x;
    const int t = threadIdx.x;

    if (b < NCONV) {
        int i = b * 256 + t;
        float4 v = reinterpret_cast<const float4*>(x)[i];
        half4 h;
        h[0] = (_Float16)v.x; h[1] = (_Float16)v.y;
        h[2] = (_Float16)v.z; h[3] = (_Float16)v.w;
        reinterpret_cast<half4*>(hp)[i] = h;
        if (b == 0 && t == 0) {
            *acc_pack = 0ull;
            *counter = 0u;
        }
        return;
    }

    __shared__ float rows[CCAP * RPITCH];   // 65792 B
    __shared__ float sqv[CCAP];
    __shared__ int dpv[CCAP];               // sqd bits (>=0 -> int cmp ok)
    __shared__ int mem[CCAP];
    __shared__ int nmem;

    const int c = b - NCONV;
    if (t == 0) nmem = 0;
    if (t < CCAP) dpv[t] = 0;
    __syncthreads();
    for (int base = 0; base < N; base += 256) {
        int j = base + t;
        if (labels[j] == c) {
            int p = atomicAdd(&nmem, 1);
            if (p < CCAP) mem[p] = j;
        }
    }
    __syncthreads();
    const int M = nmem < CCAP ? nmem : CCAP;

    for (int r = 0; r < M; ++r)
        rows[r * RPITCH + t] = x[(size_t)mem[r] * D + t];
    __syncthreads();

    if (t < M) {
        const float* rp = &rows[t * RPITCH];
        float s = 0.0f;
        for (int d = 0; d < D; ++d) s += rp[d] * rp[d];
        sqv[t] = s;
    }
    __syncthreads();

    for (int p = t; p < M * M; p += 256) {
        int i = p / M, j = p - i * M;
        const float* ri = &rows[i * RPITCH];
        const float* rj = &rows[j * RPITCH];
        float dot = 0.0f;
        for (int d = 0; d < D; ++d) dot = fmaf(ri[d], rj[d], dot);
        float sqd = fmaxf(sqv[i] + sqv[j] - 2.0f * dot, 0.0f);
        if (j != i) atomicMax(&dpv[i], __float_as_int(sqd));
    }
    __syncthreads();
    if (t < M)
        dpos[mem[t]] = (M > 1) ? sqrtf(__int_as_float(dpv[t])) : -1.0f;
}

// ---------------------------------------------------------------------------
// k_main: symmetric fp16 MFMA GEMM, 8 waves (2x4), 64x32/wave, acc + accT.
// Key-free epilogue: min-dist == max-acc; track an = max a over diff-label,
// ag = max a over {diff-label, a < aHi}. fmax associative -> plain partial
// stores deterministic. 0-conflict swizzle staging.
// ---------------------------------------------------------------------------
__global__ __launch_bounds__(512) void k_main(const _Float16* __restrict__ hp,
                                              const int* __restrict__ labels,
                                              const float* __restrict__ dpos,
                                              float* __restrict__ pr_n,
                                              float* __restrict__ pr_s,
                                              float* __restrict__ pc_n,
                                              float* __restrict__ pc_s) {
    __shared__ char Abuf[2][BM * 128];   // 16 KB each
    __shared__ char Bbuf[2][BN * 128];
    __shared__ float rHi[BM], cHi[BN];
    __shared__ int rlab[BM], clab[BN];
    __shared__ float tmpn[4][BM], tmps[4][BM];

    const int t = threadIdx.x;
    int tb = blockIdx.x;
    // triangular decode: tb -> (by, bx), by <= bx
    int by = (int)((2 * NB + 1 - sqrtf((float)((2 * NB + 1) * (2 * NB + 1)) -
                                       8.0f * (float)tb)) * 0.5f);
    if (by < 0) by = 0;
    if (by > NB - 1) by = NB - 1;
    while (by > 0 && (by * NB - by * (by - 1) / 2) > tb) --by;
    while (((by + 1) * NB - (by + 1) * by / 2) <= tb) ++by;
    const int bx = by + (tb - (by * NB - by * (by - 1) / 2));
    const int r0 = by * BM, c0 = bx * BN;

    const int w = t >> 6, lane = t & 63;
    const int wr = w >> 2, wc = w & 3;   // 2x4 wave grid; 64x32 per wave

    if (t < BM) {
        rlab[t] = labels[r0 + t];
        float dp = dpos[r0 + t];
        rHi[t] = (2.0f - dp * dp) * 0.5f;   // a < aHi <=> dist > dp
    } else if (t < 256) {
        int u = t - BM;
        clab[u] = labels[c0 + u];
        float dp = dpos[c0 + u];
        cHi[u] = (2.0f - dp * dp) * 0.5f;
    }

    f32x4 acc[4][2] = {};    // [m][n]
    f32x4 accT[2][4] = {};   // [n][m]

    const int srow = lane >> 3;
    const int scol = ((lane & 7) ^ srow) << 3;   // fp16-elem offset
    const _Float16* gA0 = hp + (size_t)(r0 + srow) * D + scol + (size_t)w * 8 * D;
    const _Float16* gB0 = hp + (size_t)(c0 + srow) * D + scol + (size_t)w * 8 * D;
    const int ldso = w * 1024 + lane * 16;

#define STAGE(bufA, bufB, k0e)                                                  \
    {                                                                           \
        _Pragma("unroll")                                                       \
        for (int q = 0; q < 2; ++q) {                                           \
            const _Float16* gpa = gA0 + q * (8 * 8 * D) + (k0e);                \
            const _Float16* gpb = gB0 + q * (8 * 8 * D) + (k0e);                \
            char* lpa = (bufA) + q * 8192 + ldso;                               \
            char* lpb = (bufB) + q * 8192 + ldso;                               \
            __builtin_amdgcn_global_load_lds(                                   \
                (__attribute__((address_space(1))) void*)(void*)gpa,            \
                (__attribute__((address_space(3))) void*)lpa, 16, 0, 0);        \
            __builtin_amdgcn_global_load_lds(                                   \
                (__attribute__((address_space(1))) void*)(void*)gpb,            \
                (__attribute__((address_space(3))) void*)lpb, 16, 0, 0);        \
        }                                                                       \
    }

    STAGE(Abuf[0], Bbuf[0], 0);
    asm volatile("s_waitcnt vmcnt(0)" ::: "memory");
    __syncthreads();

    const int g2 = lane >> 4;
    const int lr = lane & 15;
    const int rsw = lr & 7;

#pragma unroll 1
    for (int s = 0; s < NCH; ++s) {
        const int cur = s & 1;
        if (s < NCH - 1) STAGE(Abuf[cur ^ 1], Bbuf[cur ^ 1], (s + 1) * 64);

#pragma unroll
        for (int kk = 0; kk < 2; ++kk) {
            const int cb = kk * 64 + (g2 << 4);
            half8 aF[4], bF[2];
#pragma unroll
            for (int m = 0; m < 4; ++m) {
                int ra = wr * 64 + m * 16 + lr;
                aF[m] = *reinterpret_cast<const half8*>(
                    Abuf[cur] + ra * 128 + (cb ^ (rsw << 4)));
            }
#pragma unroll
            for (int n = 0; n < 2; ++n) {
                int rb = wc * 32 + n * 16 + lr;
                bF[n] = *reinterpret_cast<const half8*>(
                    Bbuf[cur] + rb * 128 + (cb ^ (rsw << 4)));
            }
#pragma unroll
            for (int m = 0; m < 4; ++m)
#pragma unroll
                for (int n = 0; n < 2; ++n)
                    acc[m][n] = __builtin_amdgcn_mfma_f32_16x16x32_f16(
                        aF[m], bF[n], acc[m][n], 0, 0, 0);
#pragma unroll
            for (int n = 0; n < 2; ++n)
#pragma unroll
                for (int m = 0; m < 4; ++m)
                    accT[n][m] = __builtin_amdgcn_mfma_f32_16x16x32_f16(
                        bF[n], aF[m], accT[n][m], 0, 0, 0);
        }
        __syncthreads();
    }
#undef STAGE

    // ---- epilogue: key-free float maxima ----
    const float NINF = -__builtin_inff();

    int rowm[4]; int rlm[4]; float rHim[4];
#pragma unroll
    for (int m = 0; m < 4; ++m) {
        rowm[m] = wr * 64 + m * 16 + lr;
        rlm[m] = rlab[rowm[m]];
        rHim[m] = rHi[rowm[m]];
    }
    int4 clA = *reinterpret_cast<const int4*>(&clab[wc * 32 + g2 * 4]);
    int4 clB = *reinterpret_cast<const int4*>(&clab[wc * 32 + 16 + g2 * 4]);
    const int clv[8] = {clA.x, clA.y, clA.z, clA.w, clB.x, clB.y, clB.z, clB.w};
    int coln[2]; int cln[2]; float cHin[2];
#pragma unroll
    for (int n = 0; n < 2; ++n) {
        coln[n] = wc * 32 + n * 16 + lr;
        cln[n] = clab[coln[n]];
        cHin[n] = cHi[coln[n]];
    }
    int rlq[16];
#pragma unroll
    for (int m = 0; m < 4; ++m) {
        int4 rv = *reinterpret_cast<const int4*>(&rlab[wr * 64 + m * 16 + g2 * 4]);
        rlq[m * 4 + 0] = rv.x; rlq[m * 4 + 1] = rv.y;
        rlq[m * 4 + 2] = rv.z; rlq[m * 4 + 3] = rv.w;
    }

    // row pass via accT
#pragma unroll
    for (int m = 0; m < 4; ++m) {
        const int rl = rlm[m];
        const float aHi = rHim[m];
        float an = NINF, ag = NINF;
#pragma unroll
        for (int n = 0; n < 2; ++n)
#pragma unroll
            for (int reg = 0; reg < 4; ++reg) {
                float a = accT[n][m][reg];
                bool neq = (rl != clv[n * 4 + reg]);
                an = fmaxf(an, neq ? a : NINF);
                ag = fmaxf(ag, (neq && a < aHi) ? a : NINF);
            }
        an = fmaxf(an, __shfl_xor(an, 16, 64));
        an = fmaxf(an, __shfl_xor(an, 32, 64));
        ag = fmaxf(ag, __shfl_xor(ag, 16, 64));
        ag = fmaxf(ag, __shfl_xor(ag, 32, 64));
        if (g2 == 0) {
            tmpn[wc][rowm[m]] = an;
            tmps[wc][rowm[m]] = ag;
        }
    }
    __syncthreads();
    if (t < BM) {
        float a0 = fmaxf(tmpn[0][t], tmpn[1][t]);
        float a1 = fmaxf(tmpn[2][t], tmpn[3][t]);
        pr_n[(size_t)tb * BM + t] = fmaxf(a0, a1);
        float b0 = fmaxf(tmps[0][t], tmps[1][t]);
        float b1 = fmaxf(tmps[2][t], tmps[3][t]);
        pr_s[(size_t)tb * BM + t] = fmaxf(b0, b1);
    }
    __syncthreads();

    // col pass via acc
#pragma unroll
    for (int n = 0; n < 2; ++n) {
        const int cl = cln[n];
        const float aHi = cHin[n];
        float an = NINF, ag = NINF;
#pragma unroll
        for (int m = 0; m < 4; ++m)
#pragma unroll
            for (int reg = 0; reg < 4; ++reg) {
                float a = acc[m][n][reg];
                bool neq = (cl != rlq[m * 4 + reg]);
                an = fmaxf(an, neq ? a : NINF);
                ag = fmaxf(ag, (neq && a < aHi) ? a : NINF);
            }
        an = fmaxf(an, __shfl_xor(an, 16, 64));
        an = fmaxf(an, __shfl_xor(an, 32, 64));
        ag = fmaxf(ag, __shfl_xor(ag, 16, 64));
        ag = fmaxf(ag, __shfl_xor(ag, 32, 64));
        if (lane < 16) {
            tmpn[wr][coln[n]] = an;
            tmps[wr][coln[n]] = ag;
        }
    }
    __syncthreads();
    if (t < BN) {
        pc_n[(size_t)tb * BN + t] = fmaxf(tmpn[0][t], tmpn[1][t]);
        pc_s[(size_t)tb * BN + t] = fmaxf(tmps[0][t], tmps[1][t]);
    }
}

// ---------------------------------------------------------------------------
// k_finish: 64 blocks; coalesced fmax folds of the per-tile partials; loss
// from exact f32 maxima; deterministic packed-integer atomicAdd finish.
// ---------------------------------------------------------------------------
__global__ __launch_bounds__(256) void k_finish(const float* __restrict__ dpos,
                                                const float* __restrict__ pr_n,
                                                const float* __restrict__ pr_s,
                                                const float* __restrict__ pc_n,
                                                const float* __restrict__ pc_s,
                                                u64* __restrict__ acc_pack,
                                                unsigned* __restrict__ counter,
                                                float* __restrict__ out) {
    __shared__ float shn[2][128], shs[2][128];
    __shared__ u64 wpart[2];
    const int q = blockIdx.x;
    const int t = threadIdx.x;
    const int half = t >> 7, a = t & 127;
    const int Lr = NB - q;
    const int base = q * NB - q * (q - 1) / 2;
    const int ntiles = Lr + q + 1;
    const float NINF = -__builtin_inff();

    float an = NINF, ag = NINF;
    for (int u = half; u < ntiles; u += 2) {
        size_t off;
        const float *Pn, *Ps;
        if (u < Lr) {
            off = (size_t)(base + u) * BM + a;
            Pn = pr_n; Ps = pr_s;
        } else {
            int byy = u - Lr;
            int tb2 = byy * NB - byy * (byy - 1) / 2 + (q - byy);
            off = (size_t)tb2 * BN + a;
            Pn = pc_n; Ps = pc_s;
        }
        an = fmaxf(an, Pn[off]);
        ag = fmaxf(ag, Ps[off]);
    }
    shn[half][a] = an;
    shs[half][a] = ag;
    __syncthreads();

    u64 pack = 0;
    if (t < 128) {
        an = fmaxf(shn[0][t], shn[1][t]);
        ag = fmaxf(shs[0][t], shs[1][t]);
        float dp = dpos[q * 128 + t];
        if (dp >= 0.0f && an > -1e37f) {
            float dphi = dp + MARGIN;
            float aLo = (2.0f - dphi * dphi) * 0.5f;   // a > aLo <=> dist < dp+m
            float asel = (ag > aLo) ? ag : an;
            float fsq = fmaxf(fmaf(-2.0f, asel, 2.0f), 0.0f);
            float dn = sqrtf(fsq);
            float l = fmaxf(dp - dn + MARGIN, 0.0f);
            u64 lq = (u64)(l * 1073741824.0f + 0.5f);   // 2^30 fixed point
            pack = (lq << 16) | 1ull;
        }
    }
    for (int m = 1; m <= 32; m <<= 1) pack += __shfl_xor(pack, m, 64);
    if (t < 128 && (t & 63) == 0) wpart[t >> 6] = pack;
    __syncthreads();
    if (t == 0) {
        atomicAdd(acc_pack, wpart[0] + wpart[1]);
        __threadfence();
        unsigned old = atomicAdd(counter, 1u);
        if (old == gridDim.x - 1) {
            u64 val = atomicAdd(acc_pack, (u64)0);
            double s = (double)(val >> 16) * (1.0 / 1073741824.0);
            double c = (double)(val & 0xFFFFull);
            out[0] = (float)(s / c);
        }
    }
}

// ---------------------------------------------------------------------------
extern "C" void kernel_launch(void* const* d_in, const int* in_sizes, int n_in,
                              void* d_out, int out_size, void* d_ws, size_t ws_size,
                              hipStream_t stream) {
    const float* x = (const float*)d_in[0];
    const int* labels = (const int*)d_in[1];
    float* out = (float*)d_out;

    u64* acc_pack = (u64*)d_ws;
    unsigned* counter = (unsigned*)(acc_pack + 1);
    float* dpos = (float*)(counter + 2);
    _Float16* hp = (_Float16*)(dpos + N);
    float* pr_n = (float*)(hp + (size_t)N * D);
    float* pr_s = pr_n + (size_t)NTRI * BM;
    float* pc_n = pr_s + (size_t)NTRI * BM;
    float* pc_s = pc_n + (size_t)NTRI * BM;

    hipLaunchKernelGGL(k_prep, dim3(NCONV + NCLS), dim3(256), 0, stream,
                       x, labels, hp, dpos, acc_pack, counter);
    hipLaunchKernelGGL(k_main, dim3(NTRI), dim3(512), 0, stream,
                       hp, labels, dpos, pr_n, pr_s, pc_n, pc_s);
    hipLaunchKernelGGL(k_finish, dim3(NB), dim3(256), 0, stream,
                       dpos, pr_n, pr_s, pc_n, pc_s, acc_pack, counter, out);
}

// Round 20
// 94.180 us; speedup vs baseline: 1.6540x; 1.0288x over previous
//
#include <hip/hip_runtime.h>
#include <hip/hip_bf16.h>
#include <math.h>

#define N 8192
#define D 256
#define MARGIN 1.0f

#define BM 128
#define BN 128
#define NCH 4            // K-chunks of 64 fp16 elems (128B per row)
#define NB (N / BM)      // 64
#define NTRI (NB * (NB + 1) / 2)   // 2080
#define CONVB 512        // conversion blocks (grid-strided 4x)
#define NCLS 512
#define CCAP 64          // class member capacity (mean 16)
#define RPITCH 260       // padded row pitch (floats): 1040 B = 16B-aligned,
                         // bank stride 4 -> ~2-way (free) on float4 reads

typedef __attribute__((ext_vector_type(8))) _Float16 half8;
typedef __attribute__((ext_vector_type(4))) _Float16 half4;
typedef __attribute__((ext_vector_type(4))) float f32x4;
typedef unsigned int uint32;
typedef unsigned long long u64;

// ---------------------------------------------------------------------------
// k_prep: blocks [0,CONVB): f32->fp16 conversion, 4 float4s per thread
// (+ block 0 zeroes the finish cells). Blocks [CONVB,+NCLS): per-class
// exact-f32 d_pos, LDS-resident, float4 dots (r15 structure, vectorized).
// ---------------------------------------------------------------------------
__global__ __launch_bounds__(256) void k_prep(const float* __restrict__ x,
                                              const int* __restrict__ labels,
                                              _Float16* __restrict__ hp,
                                              float* __restrict__ dpos,
                                              u64* __restrict__ acc_pack,
                                              unsigned* __restrict__ counter) {
    const int b = blockIdx.x;
    const int t = threadIdx.x;

    if (b < CONVB) {
#pragma unroll
        for (int it = 0; it < 4; ++it) {
            int i = b * 1024 + it * 256 + t;
            float4 v = reinterpret_cast<const float4*>(x)[i];
            half4 h;
            h[0] = (_Float16)v.x; h[1] = (_Float16)v.y;
            h[2] = (_Float16)v.z; h[3] = (_Float16)v.w;
            reinterpret_cast<half4*>(hp)[i] = h;
        }
        if (b == 0 && t == 0) {
            *acc_pack = 0ull;
            *counter = 0u;
        }
        return;
    }

    __shared__ __align__(16) float rows[CCAP * RPITCH];   // 66560 B
    __shared__ float sqv[CCAP];
    __shared__ int dpv[CCAP];               // sqd bits (>=0 -> int cmp ok)
    __shared__ int mem[CCAP];
    __shared__ int nmem;

    const int c = b - CONVB;
    if (t == 0) nmem = 0;
    if (t < CCAP) dpv[t] = 0;
    __syncthreads();
    for (int base = 0; base < N; base += 256) {
        int j = base + t;
        if (labels[j] == c) {
            int p = atomicAdd(&nmem, 1);
            if (p < CCAP) mem[p] = j;
        }
    }
    __syncthreads();
    const int M = nmem < CCAP ? nmem : CCAP;

    for (int r = 0; r < M; ++r)
        rows[r * RPITCH + t] = x[(size_t)mem[r] * D + t];
    __syncthreads();

    // per-member squared norm, float4
    if (t < M) {
        const float4* rp = reinterpret_cast<const float4*>(&rows[t * RPITCH]);
        float s0 = 0.0f, s1 = 0.0f;
#pragma unroll 8
        for (int k = 0; k < 64; k += 2) {
            float4 a = rp[k];
            s0 = fmaf(a.x, a.x, fmaf(a.y, a.y, fmaf(a.z, a.z, fmaf(a.w, a.w, s0))));
            float4 c4 = rp[k + 1];
            s1 = fmaf(c4.x, c4.x, fmaf(c4.y, c4.y, fmaf(c4.z, c4.z, fmaf(c4.w, c4.w, s1))));
        }
        sqv[t] = s0 + s1;
    }
    __syncthreads();

    // one thread per ordered pair (i,j); float4 dot, two chains
    for (int p = t; p < M * M; p += 256) {
        int i = p / M, j = p - i * M;
        const float4* ri = reinterpret_cast<const float4*>(&rows[i * RPITCH]);
        const float4* rj = reinterpret_cast<const float4*>(&rows[j * RPITCH]);
        float d0 = 0.0f, d1 = 0.0f;
#pragma unroll 8
        for (int k = 0; k < 64; k += 2) {
            float4 a = ri[k], v = rj[k];
            d0 = fmaf(a.x, v.x, fmaf(a.y, v.y, fmaf(a.z, v.z, fmaf(a.w, v.w, d0))));
            float4 a1 = ri[k + 1], v1 = rj[k + 1];
            d1 = fmaf(a1.x, v1.x, fmaf(a1.y, v1.y, fmaf(a1.z, v1.z, fmaf(a1.w, v1.w, d1))));
        }
        float sqd = fmaxf(sqv[i] + sqv[j] - 2.0f * (d0 + d1), 0.0f);
        if (j != i) atomicMax(&dpv[i], __float_as_int(sqd));
    }
    __syncthreads();
    if (t < M)
        dpos[mem[t]] = (M > 1) ? sqrtf(__int_as_float(dpv[t])) : -1.0f;
}

// ---------------------------------------------------------------------------
// k_main: symmetric fp16 MFMA GEMM, 8 waves (2x4), 64x32/wave, acc + accT.
// Key-free epilogue: min-dist == max-acc; track an = max a over diff-label,
// ag = max a over {diff-label, a < aHi}. fmax associative -> plain partial
// stores deterministic. 0-conflict swizzle staging. (FROZEN from r15/r19.)
// ---------------------------------------------------------------------------
__global__ __launch_bounds__(512) void k_main(const _Float16* __restrict__ hp,
                                              const int* __restrict__ labels,
                                              const float* __restrict__ dpos,
                                              float* __restrict__ pr_n,
                                              float* __restrict__ pr_s,
                                              float* __restrict__ pc_n,
                                              float* __restrict__ pc_s) {
    __shared__ char Abuf[2][BM * 128];   // 16 KB each
    __shared__ char Bbuf[2][BN * 128];
    __shared__ float rHi[BM], cHi[BN];
    __shared__ int rlab[BM], clab[BN];
    __shared__ float tmpn[4][BM], tmps[4][BM];

    const int t = threadIdx.x;
    int tb = blockIdx.x;
    // triangular decode: tb -> (by, bx), by <= bx
    int by = (int)((2 * NB + 1 - sqrtf((float)((2 * NB + 1) * (2 * NB + 1)) -
                                       8.0f * (float)tb)) * 0.5f);
    if (by < 0) by = 0;
    if (by > NB - 1) by = NB - 1;
    while (by > 0 && (by * NB - by * (by - 1) / 2) > tb) --by;
    while (((by + 1) * NB - (by + 1) * by / 2) <= tb) ++by;
    const int bx = by + (tb - (by * NB - by * (by - 1) / 2));
    const int r0 = by * BM, c0 = bx * BN;

    const int w = t >> 6, lane = t & 63;
    const int wr = w >> 2, wc = w & 3;   // 2x4 wave grid; 64x32 per wave

    if (t < BM) {
        rlab[t] = labels[r0 + t];
        float dp = dpos[r0 + t];
        rHi[t] = (2.0f - dp * dp) * 0.5f;   // a < aHi <=> dist > dp
    } else if (t < 256) {
        int u = t - BM;
        clab[u] = labels[c0 + u];
        float dp = dpos[c0 + u];
        cHi[u] = (2.0f - dp * dp) * 0.5f;
    }

    f32x4 acc[4][2] = {};    // [m][n]
    f32x4 accT[2][4] = {};   // [n][m]

    const int srow = lane >> 3;
    const int scol = ((lane & 7) ^ srow) << 3;   // fp16-elem offset
    const _Float16* gA0 = hp + (size_t)(r0 + srow) * D + scol + (size_t)w * 8 * D;
    const _Float16* gB0 = hp + (size_t)(c0 + srow) * D + scol + (size_t)w * 8 * D;
    const int ldso = w * 1024 + lane * 16;

#define STAGE(bufA, bufB, k0e)                                                  \
    {                                                                           \
        _Pragma("unroll")                                                       \
        for (int q = 0; q < 2; ++q) {                                           \
            const _Float16* gpa = gA0 + q * (8 * 8 * D) + (k0e);                \
            const _Float16* gpb = gB0 + q * (8 * 8 * D) + (k0e);                \
            char* lpa = (bufA) + q * 8192 + ldso;                               \
            char* lpb = (bufB) + q * 8192 + ldso;                               \
            __builtin_amdgcn_global_load_lds(                                   \
                (__attribute__((address_space(1))) void*)(void*)gpa,            \
                (__attribute__((address_space(3))) void*)lpa, 16, 0, 0);        \
            __builtin_amdgcn_global_load_lds(                                   \
                (__attribute__((address_space(1))) void*)(void*)gpb,            \
                (__attribute__((address_space(3))) void*)lpb, 16, 0, 0);        \
        }                                                                       \
    }

    STAGE(Abuf[0], Bbuf[0], 0);
    asm volatile("s_waitcnt vmcnt(0)" ::: "memory");
    __syncthreads();

    const int g2 = lane >> 4;
    const int lr = lane & 15;
    const int rsw = lr & 7;

#pragma unroll 1
    for (int s = 0; s < NCH; ++s) {
        const int cur = s & 1;
        if (s < NCH - 1) STAGE(Abuf[cur ^ 1], Bbuf[cur ^ 1], (s + 1) * 64);

#pragma unroll
        for (int kk = 0; kk < 2; ++kk) {
            const int cb = kk * 64 + (g2 << 4);
            half8 aF[4], bF[2];
#pragma unroll
            for (int m = 0; m < 4; ++m) {
                int ra = wr * 64 + m * 16 + lr;
                aF[m] = *reinterpret_cast<const half8*>(
                    Abuf[cur] + ra * 128 + (cb ^ (rsw << 4)));
            }
#pragma unroll
            for (int n = 0; n < 2; ++n) {
                int rb = wc * 32 + n * 16 + lr;
                bF[n] = *reinterpret_cast<const half8*>(
                    Bbuf[cur] + rb * 128 + (cb ^ (rsw << 4)));
            }
#pragma unroll
            for (int m = 0; m < 4; ++m)
#pragma unroll
                for (int n = 0; n < 2; ++n)
                    acc[m][n] = __builtin_amdgcn_mfma_f32_16x16x32_f16(
                        aF[m], bF[n], acc[m][n], 0, 0, 0);
#pragma unroll
            for (int n = 0; n < 2; ++n)
#pragma unroll
                for (int m = 0; m < 4; ++m)
                    accT[n][m] = __builtin_amdgcn_mfma_f32_16x16x32_f16(
                        bF[n], aF[m], accT[n][m], 0, 0, 0);
        }
        __syncthreads();
    }
#undef STAGE

    // ---- epilogue: key-free float maxima ----
    const float NINF = -__builtin_inff();

    int rowm[4]; int rlm[4]; float rHim[4];
#pragma unroll
    for (int m = 0; m < 4; ++m) {
        rowm[m] = wr * 64 + m * 16 + lr;
        rlm[m] = rlab[rowm[m]];
        rHim[m] = rHi[rowm[m]];
    }
    int4 clA = *reinterpret_cast<const int4*>(&clab[wc * 32 + g2 * 4]);
    int4 clB = *reinterpret_cast<const int4*>(&clab[wc * 32 + 16 + g2 * 4]);
    const int clv[8] = {clA.x, clA.y, clA.z, clA.w, clB.x, clB.y, clB.z, clB.w};
    int coln[2]; int cln[2]; float cHin[2];
#pragma unroll
    for (int n = 0; n < 2; ++n) {
        coln[n] = wc * 32 + n * 16 + lr;
        cln[n] = clab[coln[n]];
        cHin[n] = cHi[coln[n]];
    }
    int rlq[16];
#pragma unroll
    for (int m = 0; m < 4; ++m) {
        int4 rv = *reinterpret_cast<const int4*>(&rlab[wr * 64 + m * 16 + g2 * 4]);
        rlq[m * 4 + 0] = rv.x; rlq[m * 4 + 1] = rv.y;
        rlq[m * 4 + 2] = rv.z; rlq[m * 4 + 3] = rv.w;
    }

    // row pass via accT
#pragma unroll
    for (int m = 0; m < 4; ++m) {
        const int rl = rlm[m];
        const float aHi = rHim[m];
        float an = NINF, ag = NINF;
#pragma unroll
        for (int n = 0; n < 2; ++n)
#pragma unroll
            for (int reg = 0; reg < 4; ++reg) {
                float a = accT[n][m][reg];
                bool neq = (rl != clv[n * 4 + reg]);
                an = fmaxf(an, neq ? a : NINF);
                ag = fmaxf(ag, (neq && a < aHi) ? a : NINF);
            }
        an = fmaxf(an, __shfl_xor(an, 16, 64));
        an = fmaxf(an, __shfl_xor(an, 32, 64));
        ag = fmaxf(ag, __shfl_xor(ag, 16, 64));
        ag = fmaxf(ag, __shfl_xor(ag, 32, 64));
        if (g2 == 0) {
            tmpn[wc][rowm[m]] = an;
            tmps[wc][rowm[m]] = ag;
        }
    }
    __syncthreads();
    if (t < BM) {
        float a0 = fmaxf(tmpn[0][t], tmpn[1][t]);
        float a1 = fmaxf(tmpn[2][t], tmpn[3][t]);
        pr_n[(size_t)tb * BM + t] = fmaxf(a0, a1);
        float b0 = fmaxf(tmps[0][t], tmps[1][t]);
        float b1 = fmaxf(tmps[2][t], tmps[3][t]);
        pr_s[(size_t)tb * BM + t] = fmaxf(b0, b1);
    }
    __syncthreads();

    // col pass via acc
#pragma unroll
    for (int n = 0; n < 2; ++n) {
        const int cl = cln[n];
        const float aHi = cHin[n];
        float an = NINF, ag = NINF;
#pragma unroll
        for (int m = 0; m < 4; ++m)
#pragma unroll
            for (int reg = 0; reg < 4; ++reg) {
                float a = acc[m][n][reg];
                bool neq = (cl != rlq[m * 4 + reg]);
                an = fmaxf(an, neq ? a : NINF);
                ag = fmaxf(ag, (neq && a < aHi) ? a : NINF);
            }
        an = fmaxf(an, __shfl_xor(an, 16, 64));
        an = fmaxf(an, __shfl_xor(an, 32, 64));
        ag = fmaxf(ag, __shfl_xor(ag, 16, 64));
        ag = fmaxf(ag, __shfl_xor(ag, 32, 64));
        if (lane < 16) {
            tmpn[wr][coln[n]] = an;
            tmps[wr][coln[n]] = ag;
        }
    }
    __syncthreads();
    if (t < BN) {
        pc_n[(size_t)tb * BN + t] = fmaxf(tmpn[0][t], tmpn[1][t]);
        pc_s[(size_t)tb * BN + t] = fmaxf(tmps[0][t], tmps[1][t]);
    }
}

// ---------------------------------------------------------------------------
// k_finish: 64 blocks; coalesced fmax folds of the per-tile partials; loss
// from exact f32 maxima; deterministic packed-integer atomicAdd finish.
// ---------------------------------------------------------------------------
__global__ __launch_bounds__(256) void k_finish(const float* __restrict__ dpos,
                                                const float* __restrict__ pr_n,
                                                const float* __restrict__ pr_s,
                                                const float* __restrict__ pc_n,
                                                const float* __restrict__ pc_s,
                                                u64* __restrict__ acc_pack,
                                                unsigned* __restrict__ counter,
                                                float* __restrict__ out) {
    __shared__ float shn[2][128], shs[2][128];
    __shared__ u64 wpart[2];
    const int q = blockIdx.x;
    const int t = threadIdx.x;
    const int half = t >> 7, a = t & 127;
    const int Lr = NB - q;
    const int base = q * NB - q * (q - 1) / 2;
    const int ntiles = Lr + q + 1;
    const float NINF = -__builtin_inff();

    float an = NINF, ag = NINF;
    for (int u = half; u < ntiles; u += 2) {
        size_t off;
        const float *Pn, *Ps;
        if (u < Lr) {
            off = (size_t)(base + u) * BM + a;
            Pn = pr_n; Ps = pr_s;
        } else {
            int byy = u - Lr;
            int tb2 = byy * NB - byy * (byy - 1) / 2 + (q - byy);
            off = (size_t)tb2 * BN + a;
            Pn = pc_n; Ps = pc_s;
        }
        an = fmaxf(an, Pn[off]);
        ag = fmaxf(ag, Ps[off]);
    }
    shn[half][a] = an;
    shs[half][a] = ag;
    __syncthreads();

    u64 pack = 0;
    if (t < 128) {
        an = fmaxf(shn[0][t], shn[1][t]);
        ag = fmaxf(shs[0][t], shs[1][t]);
        float dp = dpos[q * 128 + t];
        if (dp >= 0.0f && an > -1e37f) {
            float dphi = dp + MARGIN;
            float aLo = (2.0f - dphi * dphi) * 0.5f;   // a > aLo <=> dist < dp+m
            float asel = (ag > aLo) ? ag : an;
            float fsq = fmaxf(fmaf(-2.0f, asel, 2.0f), 0.0f);
            float dn = sqrtf(fsq);
            float l = fmaxf(dp - dn + MARGIN, 0.0f);
            u64 lq = (u64)(l * 1073741824.0f + 0.5f);   // 2^30 fixed point
            pack = (lq << 16) | 1ull;
        }
    }
    for (int m = 1; m <= 32; m <<= 1) pack += __shfl_xor(pack, m, 64);
    if (t < 128 && (t & 63) == 0) wpart[t >> 6] = pack;
    __syncthreads();
    if (t == 0) {
        atomicAdd(acc_pack, wpart[0] + wpart[1]);
        __threadfence();
        unsigned old = atomicAdd(counter, 1u);
        if (old == gridDim.x - 1) {
            u64 val = atomicAdd(acc_pack, (u64)0);
            double s = (double)(val >> 16) * (1.0 / 1073741824.0);
            double c = (double)(val & 0xFFFFull);
            out[0] = (float)(s / c);
        }
    }
}

// ---------------------------------------------------------------------------
extern "C" void kernel_launch(void* const* d_in, const int* in_sizes, int n_in,
                              void* d_out, int out_size, void* d_ws, size_t ws_size,
                              hipStream_t stream) {
    const float* x = (const float*)d_in[0];
    const int* labels = (const int*)d_in[1];
    float* out = (float*)d_out;

    u64* acc_pack = (u64*)d_ws;
    unsigned* counter = (unsigned*)(acc_pack + 1);
    float* dpos = (float*)(counter + 2);
    _Float16* hp = (_Float16*)(dpos + N);
    float* pr_n = (float*)(hp + (size_t)N * D);
    float* pr_s = pr_n + (size_t)NTRI * BM;
    float* pc_n = pr_s + (size_t)NTRI * BM;
    float* pc_s = pc_n + (size_t)NTRI * BM;

    hipLaunchKernelGGL(k_prep, dim3(CONVB + NCLS), dim3(256), 0, stream,
                       x, labels, hp, dpos, acc_pack, counter);
    hipLaunchKernelGGL(k_main, dim3(NTRI), dim3(512), 0, stream,
                       hp, labels, dpos, pr_n, pr_s, pc_n, pc_s);
    hipLaunchKernelGGL(k_finish, dim3(NB), dim3(256), 0, stream,
                       dpos, pr_n, pr_s, pc_n, pc_s, acc_pack, counter, out);
}